// Round 1
// baseline (163.185 us; speedup 1.0000x reference)
//
#include <hip/hip_runtime.h>
#include <math.h>

// ---------------------------------------------------------------------------
// Problem: out [1, 128, N] f32 =
//   rows   0.. 63 : pdf^T              (pdf is [N,64] row-major)
//   rows  64.. 95 : te[c]  broadcast   (timestep embedding MLP, single vector)
//   rows  96..127 : mask[p] ? me1[c] : me0[c]   (mask in {0,1} -> 2 rows only)
// ---------------------------------------------------------------------------

#define HALF 32  // EMBED_DIM/2

// Tiny kernel: computes te[32], me0[32], me1[32] into ws[0..95].
// v=0 -> sinusoidal(t) through ef MLP; v=1 -> sinusoidal(0) through em MLP;
// v=2 -> sinusoidal(1) through em MLP.
__global__ void embed_small_kernel(const float* __restrict__ t,
                                   const float* __restrict__ ef_w1, const float* __restrict__ ef_b1,
                                   const float* __restrict__ ef_w2, const float* __restrict__ ef_b2,
                                   const float* __restrict__ em_w1, const float* __restrict__ em_b1,
                                   const float* __restrict__ em_w2, const float* __restrict__ em_b2,
                                   float* __restrict__ ws) {
    __shared__ float h[3][64];
    const int tid = threadIdx.x;
    const float log_scale = 0.2970934777f;  // ln(10000)/31

    if (tid < 192) {
        const int v = tid / 64;      // which value
        const int j = tid % 64;      // hidden unit
        const float val = (v == 0) ? t[0] : (float)(v - 1);
        const float* w1 = (v == 0) ? ef_w1 : em_w1;
        const float* b1 = (v == 0) ? ef_b1 : em_b1;
        float acc = b1[j];
        for (int k = 0; k < HALF; ++k) {
            float f = expf(-(float)k * log_scale);
            float ang = val * f;
            float s, c;
            sincosf(ang, &s, &c);
            // emb[k] = sin, emb[HALF+k] = cos ; h[j] += emb[k']*w1[j][k']
            acc += s * w1[j * 64 + k] + c * w1[j * 64 + HALF + k];
        }
        // LeakyReLU(0.1)
        h[v][j] = (acc > 0.0f) ? acc : 0.1f * acc;
    }
    __syncthreads();
    if (tid < 96) {
        const int v = tid / 32;
        const int c = tid % 32;
        const float* w2 = (v == 0) ? ef_w2 : em_w2;
        const float* b2 = (v == 0) ? ef_b2 : em_b2;
        float acc = b2[c];
        const float* hh = h[v];
        for (int j = 0; j < 64; ++j) acc += hh[j] * w2[c * 64 + j];
        ws[v * 32 + c] = acc;   // ws: te[0..31], me0[32..63], me1[64..95]
    }
}

// Main streaming kernel. One block = 64 points. 256 threads.
// Phase 1: coalesced float4 loads of pdf tile -> LDS [64 pts][64 ch (+1 pad)].
// Phase 2: coalesced scalar stores; each wave writes one channel row per iter.
__global__ __launch_bounds__(256) void pvcnn_cond_kernel(
        const float* __restrict__ pdf,
        const int* __restrict__ mask,
        const float* __restrict__ ws,
        float* __restrict__ out,
        int N) {
    __shared__ float tile[64][65];
    __shared__ float emb[96];

    const int tid = threadIdx.x;
    const long long p0 = (long long)blockIdx.x * 64;
    const bool full = (p0 + 64 <= (long long)N);

    if (tid < 96) emb[tid] = ws[tid];

    // ---- load pdf tile (64 points x 64 ch = 1024 float4) ----
    if (full) {
        const float4* pdf4 = (const float4*)(pdf + p0 * 64);
        #pragma unroll
        for (int it = 0; it < 4; ++it) {
            int f = tid + it * 256;          // 0..1023
            int p = f >> 4;
            int q = f & 15;
            float4 v = pdf4[p * 16 + q];
            tile[p][4 * q + 0] = v.x;
            tile[p][4 * q + 1] = v.y;
            tile[p][4 * q + 2] = v.z;
            tile[p][4 * q + 3] = v.w;
        }
    } else {
        #pragma unroll
        for (int it = 0; it < 4; ++it) {
            int f = tid + it * 256;
            int p = f >> 4;
            int q = f & 15;
            float4 v = make_float4(0.f, 0.f, 0.f, 0.f);
            if (p0 + p < (long long)N) {
                const float4* pdf4 = (const float4*)(pdf + (p0 + p) * 64);
                v = pdf4[q];
            }
            tile[p][4 * q + 0] = v.x;
            tile[p][4 * q + 1] = v.y;
            tile[p][4 * q + 2] = v.z;
            tile[p][4 * q + 3] = v.w;
        }
    }

    const int p = tid & 63;        // point within tile
    const int wv = tid >> 6;       // wave id 0..3 -> channel sub-offset
    const bool pok = (p0 + p < (long long)N);
    int mval = 0;
    if (pok) mval = mask[p0 + p];

    __syncthreads();

    if (pok) {
        const long long col = p0 + p;
        // pdf^T rows 0..63
        #pragma unroll
        for (int cb = 0; cb < 64; cb += 4) {
            int c = cb + wv;
            out[(long long)c * N + col] = tile[p][c];
        }
        // te broadcast rows 64..95
        #pragma unroll
        for (int cb = 0; cb < 32; cb += 4) {
            int c = cb + wv;
            out[(long long)(64 + c) * N + col] = emb[c];
        }
        // mask-embedding rows 96..127
        #pragma unroll
        for (int cb = 0; cb < 32; cb += 4) {
            int c = cb + wv;
            out[(long long)(96 + c) * N + col] = mval ? emb[64 + c] : emb[32 + c];
        }
    }
}

extern "C" void kernel_launch(void* const* d_in, const int* in_sizes, int n_in,
                              void* d_out, int out_size, void* d_ws, size_t ws_size,
                              hipStream_t stream) {
    // setup_inputs order:
    // 0: inputs [1,6,N]   (only used for N; mask size also gives N)
    // 1: t [1]
    // 2: mask [N] int32
    // 3: pdf [N,64]
    // 4..7:  ef_w1, ef_b1, ef_w2, ef_b2
    // 8..11: em_w1, em_b1, em_w2, em_b2
    const float* t     = (const float*)d_in[1];
    const int*   mask  = (const int*)d_in[2];
    const float* pdf   = (const float*)d_in[3];
    const float* ef_w1 = (const float*)d_in[4];
    const float* ef_b1 = (const float*)d_in[5];
    const float* ef_w2 = (const float*)d_in[6];
    const float* ef_b2 = (const float*)d_in[7];
    const float* em_w1 = (const float*)d_in[8];
    const float* em_b1 = (const float*)d_in[9];
    const float* em_w2 = (const float*)d_in[10];
    const float* em_b2 = (const float*)d_in[11];

    float* out = (float*)d_out;
    float* ws  = (float*)d_ws;
    const int N = in_sizes[2];

    embed_small_kernel<<<1, 192, 0, stream>>>(t, ef_w1, ef_b1, ef_w2, ef_b2,
                                              em_w1, em_b1, em_w2, em_b2, ws);

    const int nblocks = (N + 63) / 64;
    pvcnn_cond_kernel<<<nblocks, 256, 0, stream>>>(pdf, mask, ws, out, N);
}